// Round 5
// baseline (916.672 us; speedup 1.0000x reference)
//
#include <hip/hip_runtime.h>

typedef short bf8_t __attribute__((ext_vector_type(8)));   // 8 bf16 (4 VGPRs)
typedef float f32x4 __attribute__((ext_vector_type(4)));
typedef unsigned short u16x4 __attribute__((ext_vector_type(4)));
typedef unsigned int u32x2 __attribute__((ext_vector_type(2)));

#define SLOPE (11.0f / 48.0f)   // RReLU eval negative slope (1/8+1/3)/2

__device__ inline unsigned short f2b(float f) {
    union { float f; unsigned int i; } v; v.f = f;
    unsigned int x = v.i;
    return (unsigned short)((x + 0x7FFFu + ((x >> 16) & 1u)) >> 16);
}
__device__ inline float b_lo(unsigned int v) {
    union { unsigned int u; float f; } c; c.u = (v & 0xffffu) << 16; return c.f;
}
__device__ inline float b_hi(unsigned int v) {
    union { unsigned int u; float f; } c; c.u = v & 0xffff0000u; return c.f;
}

// ---- fused prep: 5 weight transposes (fp32 [R,128] -> bf16 WT[128,sWT] col kOff)
//      + node_feats fp32->bf16 bulk convert ----
__global__ __launch_bounds__(256) void prep_k(
    const float* __restrict__ Wn0, const float* __restrict__ Wl0,
    const float* __restrict__ Wn1, const float* __restrict__ Wl1,
    const float* __restrict__ Wo,
    unsigned short* __restrict__ WT0, unsigned short* __restrict__ WT1,
    unsigned short* __restrict__ WTo,
    const float* __restrict__ node_feats, unsigned short* __restrict__ h0b, int n4) {
    int i = blockIdx.x * 256 + threadIdx.x;
    if (i < 131072) {
        const float* W; unsigned short* WT; int sWT, kOff, j;
        if (i < 32768)      { W = Wn0; WT = WT0; sWT = 384; kOff = 0;   j = i; }
        else if (i < 49152) { W = Wl0; WT = WT0; sWT = 384; kOff = 256; j = i - 32768; }
        else if (i < 81920) { W = Wn1; WT = WT1; sWT = 384; kOff = 0;   j = i - 49152; }
        else if (i < 98304) { W = Wl1; WT = WT1; sWT = 384; kOff = 256; j = i - 81920; }
        else                { W = Wo;  WT = WTo; sWT = 256; kOff = 0;   j = i - 98304; }
        int r = j >> 7, n = j & 127;
        WT[(size_t)n * sWT + kOff + r] = f2b(W[j]);
    } else {
        int j = i - 131072;
        if (j < n4) {
            f32x4 v = *(const f32x4*)(node_feats + (size_t)j * 4);
            u16x4 o;
            o[0] = f2b(v[0]); o[1] = f2b(v[1]); o[2] = f2b(v[2]); o[3] = f2b(v[3]);
            *(u16x4*)(h0b + (size_t)j * 4) = o;
        }
    }
}

// ---- in-degree count ----
__global__ void count_k(const int* __restrict__ dst, int* __restrict__ cnt, int E) {
    int i = blockIdx.x * 256 + threadIdx.x;
    if (i < E) atomicAdd(&cnt[dst[i]], 1);
}

// ---- exclusive prefix sum, single block: rowstart[0..N]; also seeds cursor ----
__global__ __launch_bounds__(1024) void scan_k(const int* __restrict__ cnt,
                                               int* __restrict__ rowstart,
                                               int* __restrict__ cursor, int N) {
    __shared__ int sm[1024];
    const int t = threadIdx.x;
    const int per = (N + 1023) / 1024;
    int lo = t * per, hi = lo + per < N ? lo + per : N;
    int s = 0;
    for (int i = lo; i < hi; i++) s += cnt[i];
    sm[t] = s;
    __syncthreads();
    for (int off = 1; off < 1024; off <<= 1) {
        int add = (t >= off) ? sm[t - off] : 0;
        __syncthreads();
        sm[t] += add;
        __syncthreads();
    }
    int run = (t == 0) ? 0 : sm[t - 1];
    for (int i = lo; i < hi; i++) {
        rowstart[i] = run; cursor[i] = run; run += cnt[i];
    }
    if (t == 1023) rowstart[N] = sm[1023];
}

// ---- CSR scatter: epair[pos] = {edge id, src[edge]} sorted by dst (one 8B store) ----
__global__ void scatter_k(const int* __restrict__ src, const int* __restrict__ dst,
                          int* __restrict__ cursor, int2* __restrict__ epair, int E) {
    int i = blockIdx.x * 256 + threadIdx.x;
    if (i < E) {
        int pos = atomicAdd(&cursor[dst[i]], 1);
        epair[pos] = make_int2(i, src[i]);
    }
}

// ---- per-node gather-mean: out[n] = bf16( mean of X[row] over CSR range ) ----
// One wave per node, 2 rows per iteration (half-wave each), cross-half combine
// via shfl_xor(32). ROWSEL 0: row = epair.x (edge id); 1: row = epair.y (src node).
// F32: 16B/lane f32x4; bf16: 8B/lane (4 bf16).
template <int ROWSEL, bool F32>
__global__ __launch_bounds__(256) void agg_k(
    const void* __restrict__ Xv, int sX,
    const int2* __restrict__ rows, const int* __restrict__ rowstart,
    unsigned short* __restrict__ out, int N) {
    int w = (blockIdx.x * 256 + threadIdx.x) >> 6;
    int lane = threadIdx.x & 63;
    if (w >= N) return;
    int b = rowstart[w], e = rowstart[w + 1];
    const int half = lane >> 5, l31 = lane & 31;
    float a0 = 0.f, a1 = 0.f, a2 = 0.f, a3 = 0.f;
    if constexpr (F32) {
        const float* X = (const float*)Xv;
#pragma unroll 2
        for (int i = b + half; i < e; i += 2) {
            int2 pr = rows[i];
            int r = ROWSEL ? pr.y : pr.x;
            f32x4 v = *(const f32x4*)(X + (size_t)r * sX + l31 * 4);
            a0 += v[0]; a1 += v[1]; a2 += v[2]; a3 += v[3];
        }
    } else {
        const unsigned short* X = (const unsigned short*)Xv;
#pragma unroll 2
        for (int i = b + half; i < e; i += 2) {
            int2 pr = rows[i];
            int r = ROWSEL ? pr.y : pr.x;
            u32x2 v = *(const u32x2*)(X + (size_t)r * sX + l31 * 4);
            a0 += b_lo(v[0]); a1 += b_hi(v[0]);
            a2 += b_lo(v[1]); a3 += b_hi(v[1]);
        }
    }
    a0 += __shfl_xor(a0, 32); a1 += __shfl_xor(a1, 32);
    a2 += __shfl_xor(a2, 32); a3 += __shfl_xor(a3, 32);
    if (lane < 32) {
        float inv = 1.f / fmaxf((float)(e - b), 1.f);
        u16x4 o;
        o[0] = f2b(a0 * inv); o[1] = f2b(a1 * inv);
        o[2] = f2b(a2 * inv); o[3] = f2b(a3 * inv);
        *(u16x4*)(out + (size_t)w * 128 + l31 * 4) = o;
    }
}

// ---- fused MFMA GEMM over up to 3 bf16 A-operands (K = KH*128), C[M,128] ----
// MODE 2: v = acc + bias[col] + (cnt[r]>0 ? bias2[col] : 0); rrelu; hcat[r*256+colOff+col] bf16
// MODE 3: outF[r*128+col] = acc + bias[col]                  (fp32 final output)
template <int KH, int MODE>
__global__ __launch_bounds__(256) void gemm_k(
    const unsigned short* __restrict__ A0, int s0,
    const unsigned short* __restrict__ A1, int s1,
    const unsigned short* __restrict__ A2, int s2,
    int M,
    const unsigned short* __restrict__ WT, int sWT,
    const float* __restrict__ bias, const float* __restrict__ bias2,
    const int* __restrict__ cnt,
    unsigned short* __restrict__ hcat, int colOff,
    float* __restrict__ outF) {
    // LDS: W^T tile, 128 n-rows x 128 k-cols, stride 136 (pad 8 -> conflict-light)
    __shared__ unsigned short lds[128 * 136];
    const int tid = threadIdx.x;
    const int wave = tid >> 6, lane = tid & 63;
    const int l15 = lane & 15, kg = lane >> 4;
    const int rBase = blockIdx.x * 128 + wave * 32;   // 4 waves x 32 rows

    f32x4 acc[2][8];
    const f32x4 zero = {0.f, 0.f, 0.f, 0.f};
    for (int g = 0; g < 2; g++)
        for (int t = 0; t < 8; t++) acc[g][t] = zero;

    for (int kh = 0; kh < KH; kh++) {
        const unsigned short* A = (kh == 0) ? A0 : ((kh == 1) ? A1 : A2);
        const int sA = (kh == 0) ? s0 : ((kh == 1) ? s1 : s2);
        // stage W^T 128-col slab into LDS (b128 writes)
        for (int c = tid; c < 2048; c += 256) {
            int n = c >> 4, k0 = (c & 15) << 3;
            *(bf8_t*)(lds + n * 136 + k0) =
                *(const bf8_t*)(WT + (size_t)n * sWT + kh * 128 + k0);
        }
        __syncthreads();

        int r0 = rBase + l15;       r0 = r0 < M ? r0 : M - 1;
        int r1 = rBase + 16 + l15;  r1 = r1 < M ? r1 : M - 1;
        const unsigned short* a0p = A + (size_t)r0 * sA + kg * 8;
        const unsigned short* a1p = A + (size_t)r1 * sA + kg * 8;
#pragma unroll
        for (int kc = 0; kc < 4; kc++) {
            bf8_t a0 = *(const bf8_t*)(a0p + kc * 32);
            bf8_t a1 = *(const bf8_t*)(a1p + kc * 32);
#pragma unroll
            for (int nt = 0; nt < 8; nt++) {
                bf8_t b = *(const bf8_t*)(lds + (nt * 16 + l15) * 136 + kc * 32 + kg * 8);
                acc[0][nt] = __builtin_amdgcn_mfma_f32_16x16x32_bf16(a0, b, acc[0][nt], 0, 0, 0);
                acc[1][nt] = __builtin_amdgcn_mfma_f32_16x16x32_bf16(a1, b, acc[1][nt], 0, 0, 0);
            }
        }
        if (kh + 1 < KH) __syncthreads();
    }

    // epilogue: lane holds D[m = kg*4+reg][n = l15] of each 16x16 tile
#pragma unroll
    for (int g = 0; g < 2; g++) {
#pragma unroll
        for (int reg = 0; reg < 4; reg++) {
            int r = rBase + g * 16 + kg * 4 + reg;
            if (r >= M) continue;
            if constexpr (MODE == 2) {
                float gate = (cnt[r] > 0) ? 1.f : 0.f;
#pragma unroll
                for (int nt = 0; nt < 8; nt++) {
                    int col = nt * 16 + l15;
                    float v = acc[g][nt][reg] + bias[col] + gate * bias2[col];
                    v = v >= 0.f ? v : v * SLOPE;
                    hcat[(size_t)r * 256 + colOff + col] = f2b(v);
                }
            } else {  // MODE 3: fp32 output
#pragma unroll
                for (int nt = 0; nt < 8; nt++) {
                    int col = nt * 16 + l15;
                    outF[(size_t)r * 128 + col] = acc[g][nt][reg] + bias[col];
                }
            }
        }
    }
}

extern "C" void kernel_launch(void* const* d_in, const int* in_sizes, int n_in,
                              void* d_out, int out_size, void* d_ws, size_t ws_size,
                              hipStream_t stream) {
    const float* node_feats = (const float*)d_in[0];
    const float* edge_feats = (const float*)d_in[1];
    const int* src = (const int*)d_in[2];
    const int* dst = (const int*)d_in[3];
    const float* Wn0 = (const float*)d_in[4];
    const float* bn0 = (const float*)d_in[5];
    const float* Wl0 = (const float*)d_in[6];
    const float* bl0 = (const float*)d_in[7];
    const float* Wn1 = (const float*)d_in[8];
    const float* bn1 = (const float*)d_in[9];
    const float* Wl1 = (const float*)d_in[10];
    const float* bl1 = (const float*)d_in[11];
    const float* Wo = (const float*)d_in[12];
    const float* bo = (const float*)d_in[13];

    const int N = in_sizes[0] / 128;
    const int E = in_sizes[2];

    char* ws = (char*)d_ws;
    auto take = [&](size_t bytes) {
        char* p = ws;
        ws += (bytes + 255) & ~(size_t)255;
        return p;
    };
    int* cnt = (int*)take((size_t)N * 4);
    int* rowstart = (int*)take((size_t)(N + 1) * 4);
    int* cursor = (int*)take((size_t)N * 4);
    int2* epair = (int2*)take((size_t)E * 8);
    unsigned short* h0b = (unsigned short*)take((size_t)N * 128 * 2);
    unsigned short* eaggn = (unsigned short*)take((size_t)N * 128 * 2);
    unsigned short* hsn = (unsigned short*)take((size_t)N * 128 * 2);
    unsigned short* hcat = (unsigned short*)take((size_t)N * 256 * 2);
    unsigned short* WT0 = (unsigned short*)take((size_t)128 * 384 * 2);
    unsigned short* WT1 = (unsigned short*)take((size_t)128 * 384 * 2);
    unsigned short* WTo = (unsigned short*)take((size_t)128 * 256 * 2);

    float* outF = (float*)d_out;
    const int gN = (N + 127) / 128;
    const int gE = (E + 255) / 256;
    const int n4 = N * 128 / 4;

    hipMemsetAsync(cnt, 0, (size_t)N * 4, stream);

    // fused: 5 weight transposes + node-feat bf16 convert
    prep_k<<<(131072 + n4 + 255) / 256, 256, 0, stream>>>(
        Wn0, Wl0, Wn1, Wl1, Wo, WT0, WT1, WTo, node_feats, h0b, n4);

    // CSR by dst (built once, reused by both layers)
    count_k<<<gE, 256, 0, stream>>>(dst, cnt, E);
    scan_k<<<1, 1024, 0, stream>>>(cnt, rowstart, cursor, N);
    scatter_k<<<gE, 256, 0, stream>>>(src, dst, cursor, epair, E);

    // eagg/cnt (layer-independent): mean of raw edge feats per dst node
    agg_k<0, true><<<(N + 3) / 4, 256, 0, stream>>>(edge_feats, 128, epair, rowstart, eaggn, N);

    // ---- layer 0: h1 = rrelu([hs/c | eagg/c | h0] @ [WnA;WnB;Wl] + bl + 1{c>0} bn) ----
    agg_k<1, false><<<(N + 3) / 4, 256, 0, stream>>>(h0b, 128, epair, rowstart, hsn, N);
    gemm_k<3, 2><<<gN, 256, 0, stream>>>(hsn, 128, eaggn, 128, h0b, 128, N,
        WT0, 384, bl0, bn0, cnt, hcat, 0, nullptr);

    // ---- layer 1 ----
    agg_k<1, false><<<(N + 3) / 4, 256, 0, stream>>>(hcat, 256, epair, rowstart, hsn, N);
    gemm_k<3, 2><<<gN, 256, 0, stream>>>(hsn, 128, eaggn, 128, hcat, 256, N,
        WT1, 384, bl1, bn1, cnt, hcat, 128, nullptr);

    // ---- output: [h1|h2] @ Wo + bo (fp32) ----
    gemm_k<2, 3><<<gN, 256, 0, stream>>>(hcat, 256, hcat + 128, 256, nullptr, 0, N,
        WTo, 256, bo, nullptr, nullptr, nullptr, 0, outF);
}

// Round 7
// 879.189 us; speedup vs baseline: 1.0426x; 1.0426x over previous
//
#include <hip/hip_runtime.h>

typedef short bf8_t __attribute__((ext_vector_type(8)));   // 8 bf16 (4 VGPRs)
typedef float f32x4 __attribute__((ext_vector_type(4)));
typedef unsigned short u16x4 __attribute__((ext_vector_type(4)));
typedef unsigned int u32x2 __attribute__((ext_vector_type(2)));

#define SLOPE (11.0f / 48.0f)   // RReLU eval negative slope (1/8+1/3)/2

__device__ inline unsigned short f2b(float f) {
    union { float f; unsigned int i; } v; v.f = f;
    unsigned int x = v.i;
    return (unsigned short)((x + 0x7FFFu + ((x >> 16) & 1u)) >> 16);
}
__device__ inline float b_lo(unsigned int v) {
    union { unsigned int u; float f; } c; c.u = (v & 0xffffu) << 16; return c.f;
}
__device__ inline float b_hi(unsigned int v) {
    union { unsigned int u; float f; } c; c.u = v & 0xffff0000u; return c.f;
}

// ---- fused prep: 5 weight transposes (fp32 [R,128] -> bf16 WT[128,sWT] col kOff)
//      + node_feats fp32->bf16 bulk convert + cnt zeroing ----
__global__ __launch_bounds__(256) void prep_k(
    const float* __restrict__ Wn0, const float* __restrict__ Wl0,
    const float* __restrict__ Wn1, const float* __restrict__ Wl1,
    const float* __restrict__ Wo,
    unsigned short* __restrict__ WT0, unsigned short* __restrict__ WT1,
    unsigned short* __restrict__ WTo,
    const float* __restrict__ node_feats, unsigned short* __restrict__ h0b, int n4,
    int* __restrict__ cnt, int N) {
    int i = blockIdx.x * 256 + threadIdx.x;
    if (i < 131072) {
        const float* W; unsigned short* WT; int sWT, kOff, j;
        if (i < 32768)      { W = Wn0; WT = WT0; sWT = 384; kOff = 0;   j = i; }
        else if (i < 49152) { W = Wl0; WT = WT0; sWT = 384; kOff = 256; j = i - 32768; }
        else if (i < 81920) { W = Wn1; WT = WT1; sWT = 384; kOff = 0;   j = i - 49152; }
        else if (i < 98304) { W = Wl1; WT = WT1; sWT = 384; kOff = 256; j = i - 81920; }
        else                { W = Wo;  WT = WTo; sWT = 256; kOff = 0;   j = i - 98304; }
        int r = j >> 7, n = j & 127;
        WT[(size_t)n * sWT + kOff + r] = f2b(W[j]);
    } else if (i < 131072 + n4) {
        int j = i - 131072;
        f32x4 v = *(const f32x4*)(node_feats + (size_t)j * 4);
        u16x4 o;
        o[0] = f2b(v[0]); o[1] = f2b(v[1]); o[2] = f2b(v[2]); o[3] = f2b(v[3]);
        *(u16x4*)(h0b + (size_t)j * 4) = o;
    } else {
        int j = i - 131072 - n4;
        if (j < N) cnt[j] = 0;
    }
}

// ---- in-degree count ----
__global__ void count_k(const int* __restrict__ dst, int* __restrict__ cnt, int E) {
    int i = blockIdx.x * 256 + threadIdx.x;
    if (i < E) atomicAdd(&cnt[dst[i]], 1);
}

// ---- exclusive prefix sum, single block: rowstart[0..N]; also seeds cursor ----
__global__ __launch_bounds__(1024) void scan_k(const int* __restrict__ cnt,
                                               int* __restrict__ rowstart,
                                               int* __restrict__ cursor, int N) {
    __shared__ int sm[1024];
    const int t = threadIdx.x;
    const int per = (N + 1023) / 1024;
    int lo = t * per, hi = lo + per < N ? lo + per : N;
    int s = 0;
    for (int i = lo; i < hi; i++) s += cnt[i];
    sm[t] = s;
    __syncthreads();
    for (int off = 1; off < 1024; off <<= 1) {
        int add = (t >= off) ? sm[t - off] : 0;
        __syncthreads();
        sm[t] += add;
        __syncthreads();
    }
    int run = (t == 0) ? 0 : sm[t - 1];
    for (int i = lo; i < hi; i++) {
        rowstart[i] = run; cursor[i] = run; run += cnt[i];
    }
    if (t == 1023) rowstart[N] = sm[1023];
}

// ---- CSR scatter: epair[pos] = {edge id, src[edge]} sorted by dst (one 8B store) ----
__global__ void scatter_k(const int* __restrict__ src, const int* __restrict__ dst,
                          int* __restrict__ cursor, int2* __restrict__ epair, int E) {
    int i = blockIdx.x * 256 + threadIdx.x;
    if (i < E) {
        int pos = atomicAdd(&cursor[dst[i]], 1);
        epair[pos] = make_int2(i, src[i]);
    }
}

// ---- fused layer-0 gather: per node, mean of edge rows (fp32) AND h0 rows (bf16)
// in ONE pass over the CSR range. One wave per node, 2 edges/iter (half-wave each). ----
__global__ __launch_bounds__(256) void agg0_k(
    const float* __restrict__ Ef, const unsigned short* __restrict__ H0,
    const int2* __restrict__ rows, const int* __restrict__ rowstart,
    unsigned short* __restrict__ eout, unsigned short* __restrict__ hout, int N) {
    int w = (blockIdx.x * 256 + threadIdx.x) >> 6;
    int lane = threadIdx.x & 63;
    if (w >= N) return;
    int b = rowstart[w], e = rowstart[w + 1];
    const int half = lane >> 5, l31 = lane & 31;
    float e0 = 0.f, e1 = 0.f, e2 = 0.f, e3 = 0.f;
    float h0 = 0.f, h1 = 0.f, h2 = 0.f, h3 = 0.f;
#pragma unroll 2
    for (int i = b + half; i < e; i += 2) {
        int2 pr = rows[i];
        f32x4 v = *(const f32x4*)(Ef + (size_t)pr.x * 128 + l31 * 4);
        u32x2 u = *(const u32x2*)(H0 + (size_t)pr.y * 128 + l31 * 4);
        e0 += v[0]; e1 += v[1]; e2 += v[2]; e3 += v[3];
        h0 += b_lo(u[0]); h1 += b_hi(u[0]);
        h2 += b_lo(u[1]); h3 += b_hi(u[1]);
    }
    e0 += __shfl_xor(e0, 32); e1 += __shfl_xor(e1, 32);
    e2 += __shfl_xor(e2, 32); e3 += __shfl_xor(e3, 32);
    h0 += __shfl_xor(h0, 32); h1 += __shfl_xor(h1, 32);
    h2 += __shfl_xor(h2, 32); h3 += __shfl_xor(h3, 32);
    if (lane < 32) {
        float inv = 1.f / fmaxf((float)(e - b), 1.f);
        u16x4 oe, oh;
        oe[0] = f2b(e0 * inv); oe[1] = f2b(e1 * inv);
        oe[2] = f2b(e2 * inv); oe[3] = f2b(e3 * inv);
        oh[0] = f2b(h0 * inv); oh[1] = f2b(h1 * inv);
        oh[2] = f2b(h2 * inv); oh[3] = f2b(h3 * inv);
        *(u16x4*)(eout + (size_t)w * 128 + l31 * 4) = oe;
        *(u16x4*)(hout + (size_t)w * 128 + l31 * 4) = oh;
    }
}

// ---- per-node gather-mean (bf16 source): out[n] = bf16( mean of X[epair.y] ) ----
__global__ __launch_bounds__(256) void agg_k(
    const unsigned short* __restrict__ X, int sX,
    const int2* __restrict__ rows, const int* __restrict__ rowstart,
    unsigned short* __restrict__ out, int N) {
    int w = (blockIdx.x * 256 + threadIdx.x) >> 6;
    int lane = threadIdx.x & 63;
    if (w >= N) return;
    int b = rowstart[w], e = rowstart[w + 1];
    const int half = lane >> 5, l31 = lane & 31;
    float a0 = 0.f, a1 = 0.f, a2 = 0.f, a3 = 0.f;
#pragma unroll 2
    for (int i = b + half; i < e; i += 2) {
        int2 pr = rows[i];
        u32x2 v = *(const u32x2*)(X + (size_t)pr.y * sX + l31 * 4);
        a0 += b_lo(v[0]); a1 += b_hi(v[0]);
        a2 += b_lo(v[1]); a3 += b_hi(v[1]);
    }
    a0 += __shfl_xor(a0, 32); a1 += __shfl_xor(a1, 32);
    a2 += __shfl_xor(a2, 32); a3 += __shfl_xor(a3, 32);
    if (lane < 32) {
        float inv = 1.f / fmaxf((float)(e - b), 1.f);
        u16x4 o;
        o[0] = f2b(a0 * inv); o[1] = f2b(a1 * inv);
        o[2] = f2b(a2 * inv); o[3] = f2b(a3 * inv);
        *(u16x4*)(out + (size_t)w * 128 + l31 * 4) = o;
    }
}

// ---- fused MFMA GEMM over up to 3 bf16 A-operands (K = KH*128), C[M,128] ----
// MODE 2: v = acc + bias[col] + (cnt[r]>0 ? bias2[col] : 0); rrelu; hcat[r*256+colOff+col] bf16
// MODE 3: outF[r*128+col] = acc + bias[col]                  (fp32 final output)
template <int KH, int MODE>
__global__ __launch_bounds__(256) void gemm_k(
    const unsigned short* __restrict__ A0, int s0,
    const unsigned short* __restrict__ A1, int s1,
    const unsigned short* __restrict__ A2, int s2,
    int M,
    const unsigned short* __restrict__ WT, int sWT,
    const float* __restrict__ bias, const float* __restrict__ bias2,
    const int* __restrict__ cnt,
    unsigned short* __restrict__ hcat, int colOff,
    float* __restrict__ outF) {
    // LDS: W^T tile, 128 n-rows x 128 k-cols, stride 136 (pad 8 -> conflict-light)
    __shared__ unsigned short lds[128 * 136];
    const int tid = threadIdx.x;
    const int wave = tid >> 6, lane = tid & 63;
    const int l15 = lane & 15, kg = lane >> 4;
    const int rBase = blockIdx.x * 128 + wave * 32;   // 4 waves x 32 rows

    f32x4 acc[2][8];
    const f32x4 zero = {0.f, 0.f, 0.f, 0.f};
    for (int g = 0; g < 2; g++)
        for (int t = 0; t < 8; t++) acc[g][t] = zero;

    for (int kh = 0; kh < KH; kh++) {
        const unsigned short* A = (kh == 0) ? A0 : ((kh == 1) ? A1 : A2);
        const int sA = (kh == 0) ? s0 : ((kh == 1) ? s1 : s2);
        // stage W^T 128-col slab into LDS (b128 writes)
        for (int c = tid; c < 2048; c += 256) {
            int n = c >> 4, k0 = (c & 15) << 3;
            *(bf8_t*)(lds + n * 136 + k0) =
                *(const bf8_t*)(WT + (size_t)n * sWT + kh * 128 + k0);
        }
        __syncthreads();

        int r0 = rBase + l15;       r0 = r0 < M ? r0 : M - 1;
        int r1 = rBase + 16 + l15;  r1 = r1 < M ? r1 : M - 1;
        const unsigned short* a0p = A + (size_t)r0 * sA + kg * 8;
        const unsigned short* a1p = A + (size_t)r1 * sA + kg * 8;
#pragma unroll
        for (int kc = 0; kc < 4; kc++) {
            bf8_t a0 = *(const bf8_t*)(a0p + kc * 32);
            bf8_t a1 = *(const bf8_t*)(a1p + kc * 32);
#pragma unroll
            for (int nt = 0; nt < 8; nt++) {
                bf8_t b = *(const bf8_t*)(lds + (nt * 16 + l15) * 136 + kc * 32 + kg * 8);
                acc[0][nt] = __builtin_amdgcn_mfma_f32_16x16x32_bf16(a0, b, acc[0][nt], 0, 0, 0);
                acc[1][nt] = __builtin_amdgcn_mfma_f32_16x16x32_bf16(a1, b, acc[1][nt], 0, 0, 0);
            }
        }
        if (kh + 1 < KH) __syncthreads();
    }

    // epilogue: lane holds D[m = kg*4+reg][n = l15] of each 16x16 tile
#pragma unroll
    for (int g = 0; g < 2; g++) {
#pragma unroll
        for (int reg = 0; reg < 4; reg++) {
            int r = rBase + g * 16 + kg * 4 + reg;
            if (r >= M) continue;
            if constexpr (MODE == 2) {
                float gate = (cnt[r] > 0) ? 1.f : 0.f;
#pragma unroll
                for (int nt = 0; nt < 8; nt++) {
                    int col = nt * 16 + l15;
                    float v = acc[g][nt][reg] + bias[col] + gate * bias2[col];
                    v = v >= 0.f ? v : v * SLOPE;
                    hcat[(size_t)r * 256 + colOff + col] = f2b(v);
                }
            } else {  // MODE 3: fp32 output
#pragma unroll
                for (int nt = 0; nt < 8; nt++) {
                    int col = nt * 16 + l15;
                    outF[(size_t)r * 128 + col] = acc[g][nt][reg] + bias[col];
                }
            }
        }
    }
}

extern "C" void kernel_launch(void* const* d_in, const int* in_sizes, int n_in,
                              void* d_out, int out_size, void* d_ws, size_t ws_size,
                              hipStream_t stream) {
    const float* node_feats = (const float*)d_in[0];
    const float* edge_feats = (const float*)d_in[1];
    const int* src = (const int*)d_in[2];
    const int* dst = (const int*)d_in[3];
    const float* Wn0 = (const float*)d_in[4];
    const float* bn0 = (const float*)d_in[5];
    const float* Wl0 = (const float*)d_in[6];
    const float* bl0 = (const float*)d_in[7];
    const float* Wn1 = (const float*)d_in[8];
    const float* bn1 = (const float*)d_in[9];
    const float* Wl1 = (const float*)d_in[10];
    const float* bl1 = (const float*)d_in[11];
    const float* Wo = (const float*)d_in[12];
    const float* bo = (const float*)d_in[13];

    const int N = in_sizes[0] / 128;
    const int E = in_sizes[2];

    char* ws = (char*)d_ws;
    auto take = [&](size_t bytes) {
        char* p = ws;
        ws += (bytes + 255) & ~(size_t)255;
        return p;
    };
    int* cnt = (int*)take((size_t)N * 4);
    int* rowstart = (int*)take((size_t)(N + 1) * 4);
    int* cursor = (int*)take((size_t)N * 4);
    int2* epair = (int2*)take((size_t)E * 8);
    unsigned short* h0b = (unsigned short*)take((size_t)N * 128 * 2);
    unsigned short* eaggn = (unsigned short*)take((size_t)N * 128 * 2);
    unsigned short* hsn = (unsigned short*)take((size_t)N * 128 * 2);
    unsigned short* hcat = (unsigned short*)take((size_t)N * 256 * 2);
    unsigned short* WT0 = (unsigned short*)take((size_t)128 * 384 * 2);
    unsigned short* WT1 = (unsigned short*)take((size_t)128 * 384 * 2);
    unsigned short* WTo = (unsigned short*)take((size_t)128 * 256 * 2);

    float* outF = (float*)d_out;
    const int gN = (N + 127) / 128;
    const int gE = (E + 255) / 256;
    const int n4 = N * 128 / 4;

    // fused: 5 weight transposes + node-feat bf16 convert + cnt zeroing
    prep_k<<<(131072 + n4 + N + 255) / 256, 256, 0, stream>>>(
        Wn0, Wl0, Wn1, Wl1, Wo, WT0, WT1, WTo, node_feats, h0b, n4, cnt, N);

    // CSR by dst (built once, reused by both layers)
    count_k<<<gE, 256, 0, stream>>>(dst, cnt, E);
    scan_k<<<1, 1024, 0, stream>>>(cnt, rowstart, cursor, N);
    scatter_k<<<gE, 256, 0, stream>>>(src, dst, cursor, epair, E);

    // ---- layer 0: fused gather (eagg mean + hs mean in one CSR pass) ----
    agg0_k<<<(N + 3) / 4, 256, 0, stream>>>(edge_feats, h0b, epair, rowstart,
                                            eaggn, hsn, N);
    gemm_k<3, 2><<<gN, 256, 0, stream>>>(hsn, 128, eaggn, 128, h0b, 128, N,
        WT0, 384, bl0, bn0, cnt, hcat, 0, nullptr);

    // ---- layer 1 ----
    agg_k<<<(N + 3) / 4, 256, 0, stream>>>(hcat, 256, epair, rowstart, hsn, N);
    gemm_k<3, 2><<<gN, 256, 0, stream>>>(hsn, 128, eaggn, 128, hcat, 256, N,
        WT1, 384, bl1, bn1, cnt, hcat, 128, nullptr);

    // ---- output: [h1|h2] @ Wo + bo (fp32) ----
    gemm_k<2, 3><<<gN, 256, 0, stream>>>(hcat, 256, hcat + 128, 256, nullptr, 0, N,
        WTo, 256, bo, nullptr, nullptr, nullptr, 0, outF);
}